// Round 2
// baseline (52.467 us; speedup 1.0000x reference)
//
#include <hip/hip_runtime.h>

// y[b,f] = W0[f] + W1[f] * x[b,f]
// B=4096, F=8192, fp32. Memory-bound streaming op.
// Round 2: non-temporal load/store for the zero-reuse x/y streams +
// 4x unroll (4 independent loads in flight per thread). W0/W1 (64 KiB
// total) keep cached loads — they're reused B times.

typedef float f4 __attribute__((ext_vector_type(4)));

constexpr int BLOCK = 256;
constexpr int U = 4;   // float4s per thread

__global__ void __launch_bounds__(BLOCK)
scl_kernel(const f4* __restrict__ x,
           const f4* __restrict__ W0,
           const f4* __restrict__ W1,
           f4* __restrict__ out,
           int n4, int f4mask) {
    int base = blockIdx.x * (BLOCK * U) + threadIdx.x;

    f4 xv[U];
    int idx[U];
    #pragma unroll
    for (int u = 0; u < U; ++u) {
        idx[u] = base + u * BLOCK;
        if (idx[u] < n4)
            xv[u] = __builtin_nontemporal_load(&x[idx[u]]);   // no reuse: bypass cache retention
    }

    #pragma unroll
    for (int u = 0; u < U; ++u) {
        if (idx[u] < n4) {
            int f = idx[u] & f4mask;          // F/4 = 2048 is a power of two
            f4 w0 = W0[f];                    // cached: reused by all rows
            f4 w1 = W1[f];
            f4 o  = w0 + w1 * xv[u];
            __builtin_nontemporal_store(o, &out[idx[u]]);     // streaming write
        }
    }
}

extern "C" void kernel_launch(void* const* d_in, const int* in_sizes, int n_in,
                              void* d_out, int out_size, void* d_ws, size_t ws_size,
                              hipStream_t stream) {
    const f4* x  = (const f4*)d_in[0];   // (4096, 8192)
    const f4* W0 = (const f4*)d_in[1];   // (8192,)
    const f4* W1 = (const f4*)d_in[2];   // (8192,)
    f4* out = (f4*)d_out;

    const int F = in_sizes[1];           // 8192
    const int n4 = out_size / 4;         // 8,388,608
    const int f4mask = (F / 4) - 1;      // 2047

    const int per_block = BLOCK * U;     // 1024 float4s per block
    const int grid = (n4 + per_block - 1) / per_block;   // 8192 blocks

    scl_kernel<<<grid, BLOCK, 0, stream>>>(x, W0, W1, out, n4, f4mask);
}

// Round 3
// 45.353 us; speedup vs baseline: 1.1568x; 1.1568x over previous
//
#include <hip/hip_runtime.h>

// y[b,f] = W0[f] + W1[f] * x[b,f]
// B=4096, F=8192, fp32. Memory-bound streaming op.
// Round 3: exactly round-1 structure (45.5 us) with ONE change:
// non-temporal STORE on y, so the write stream doesn't allocate in the
// 256 MB L3 and x (128 MB) can stay fully L3-resident across replays.
// Loads stay cached (round 2 proved nt-loads throw away L3 hits on x).

typedef float f4 __attribute__((ext_vector_type(4)));

__global__ void __launch_bounds__(256)
scl_kernel(const f4* __restrict__ x,
           const f4* __restrict__ W0,
           const f4* __restrict__ W1,
           f4* __restrict__ out,
           int n4, int f4mask) {
    int stride = gridDim.x * blockDim.x;
    for (int i = blockIdx.x * blockDim.x + threadIdx.x; i < n4; i += stride) {
        int f = i & f4mask;              // F/4 = 2048, power of two
        f4 xv = x[i];                    // cached: L3 can keep x resident
        f4 w0 = W0[f];                   // cached: heavy reuse
        f4 w1 = W1[f];
        f4 o  = w0 + w1 * xv;
        __builtin_nontemporal_store(o, &out[i]);   // write-only stream: don't allocate in L3
    }
}

extern "C" void kernel_launch(void* const* d_in, const int* in_sizes, int n_in,
                              void* d_out, int out_size, void* d_ws, size_t ws_size,
                              hipStream_t stream) {
    const f4* x  = (const f4*)d_in[0];   // (4096, 8192)
    const f4* W0 = (const f4*)d_in[1];   // (8192,)
    const f4* W1 = (const f4*)d_in[2];   // (8192,)
    f4* out = (f4*)d_out;

    const int F = in_sizes[1];           // 8192
    const int n4 = out_size / 4;         // 8,388,608
    const int f4mask = (F / 4) - 1;      // 2047

    const int block = 256;
    const int grid = 2048;               // 256 CU x 8 blocks, grid-stride

    scl_kernel<<<grid, block, 0, stream>>>(x, W0, W1, out, n4, f4mask);
}